// Round 11
// baseline (181.741 us; speedup 1.0000x reference)
//
#include <hip/hip_runtime.h>
#include <hip/hip_bf16.h>
#include <stdint.h>

#define S_LEN   2048
#define D_MODEL 1024
#define NH      16
#define DH      64
#define BATCH   2
#define TOKENS  (BATCH * S_LEN)   // 4096

typedef __bf16 bf16;
typedef __bf16 bf16x8 __attribute__((ext_vector_type(8)));
typedef __bf16 b16x4  __attribute__((ext_vector_type(4)));
typedef float  f32x4  __attribute__((ext_vector_type(4)));
typedef float  f32x16 __attribute__((ext_vector_type(16)));
typedef unsigned int uint32;

__device__ __forceinline__ void async_lds16(const void* g, void* l) {
  __builtin_amdgcn_global_load_lds((__attribute__((address_space(1))) void*)g,
                                   (__attribute__((address_space(3))) void*)l,
                                   16, 0, 0);
}

#define MFMA16(a, b, c) __builtin_amdgcn_mfma_f32_16x16x32_bf16((a), (b), (c), 0, 0, 0)

// ---------------------------------------------------------------------------
// fused fp32 -> bf16 bulk convert over two ranges (8 elems/thread).
// ---------------------------------------------------------------------------
__global__ __launch_bounds__(256) void convert2_kernel(
    const float* __restrict__ s0, bf16* __restrict__ d0, int n0,
    const float* __restrict__ s1, bf16* __restrict__ d1, int n1) {
  int i = blockIdx.x * 256 + threadIdx.x;
  const float* s;
  bf16* d;
  if (i < n0) {
    s = s0 + (size_t)i * 8; d = d0 + (size_t)i * 8;
  } else {
    i -= n0;
    if (i >= n1) return;
    s = s1 + (size_t)i * 8; d = d1 + (size_t)i * 8;
  }
  const f32x4 a = *(const f32x4*)s;
  const f32x4 b = *(const f32x4*)(s + 4);
  bf16x8 o;
#pragma unroll
  for (int j = 0; j < 4; j++) { o[j] = (bf16)a[j]; o[j + 4] = (bf16)b[j]; }
  *(bf16x8*)d = o;
}

// ---------------------------------------------------------------------------
// GEMM 1: 8-phase 256x256 (m201 template) — round-8 verified.
// ---------------------------------------------------------------------------
__global__ __launch_bounds__(512, 2) void gemm_qkv_kernel(
    const bf16* __restrict__ X, const bf16* __restrict__ W,
    bf16* __restrict__ Qo, bf16* __restrict__ Ko, bf16* __restrict__ VTo) {
  extern __shared__ __align__(16) bf16 smem[];
  bf16* const Asb = smem;            // [2][16384] elems (64 KB)
  bf16* const Bsb = smem + 32768;    // [2][16384] elems (64 KB)

  const int tid  = threadIdx.x;
  const int wave = tid >> 6, lane = tid & 63;
  const int quad = lane >> 4, l16 = lane & 15;
  const int wm = (wave >> 2) * 128;
  const int wn = (wave & 3) * 64;
  const int m0 = blockIdx.y * 256;
  const int n0 = blockIdx.x * 256;

  const int rowc  = tid >> 3;
  const int koffc = ((tid & 7) ^ (rowc & 7)) * 8;
  const bf16* pAlo = X + (size_t)(m0 + rowc) * D_MODEL + koffc;
  const bf16* pAhi = X + (size_t)(m0 + 128 + rowc) * D_MODEL + koffc;
  const bf16* pBlo = W + (size_t)(n0 + rowc) * D_MODEL + koffc;
  const bf16* pBhi = W + (size_t)(n0 + 128 + rowc) * D_MODEL + koffc;
  const int ldc = tid * 8;

  const int swr = l16 & 7;
  const int ko0 = ((0 + quad) ^ swr) * 8;
  const int ko1 = ((4 + quad) ^ swr) * 8;

  f32x4 acc[8][4] = {};
  bf16x8 af[4][2], bfr[4][2];

#define STG(P, LB)                                                        \
  { async_lds16((P), (LB) + ldc);                                         \
    async_lds16((P) + (size_t)64 * D_MODEL, (LB) + ldc + 4096); }

#define BAR()                                                             \
  { asm volatile("" ::: "memory");                                        \
    __builtin_amdgcn_s_barrier();                                         \
    asm volatile("" ::: "memory"); }

  STG(pAlo, Asb)                 pAlo += 64;
  STG(pAhi, Asb + 8192)          pAhi += 64;
  STG(pBlo, Bsb)                 pBlo += 64;
  STG(pBhi, Bsb + 8192)          pBhi += 64;
  STG(pAlo, Asb + 16384)         pAlo += 64;
  STG(pAhi, Asb + 16384 + 8192)  pAhi += 64;
  asm volatile("s_waitcnt vmcnt(4)" ::: "memory");
  __builtin_amdgcn_s_barrier();

#pragma unroll 2
  for (int t = 0; t < 16; t++) {
    const int cur = t & 1;
    const bf16* Ac = Asb + cur * 16384;
    const bf16* Bc = Bsb + cur * 16384;
    bf16* An = Asb + cur * 16384;
    bf16* Bn = Bsb + (cur ^ 1) * 16384;

#pragma unroll
    for (int i = 0; i < 4; i++) {
      af[i][0] = *(const bf16x8*)(Ac + (wm + i * 16 + l16) * 64 + ko0);
      af[i][1] = *(const bf16x8*)(Ac + (wm + i * 16 + l16) * 64 + ko1);
    }
#pragma unroll
    for (int j = 0; j < 2; j++) {
      bfr[j][0] = *(const bf16x8*)(Bc + (wn + j * 16 + l16) * 64 + ko0);
      bfr[j][1] = *(const bf16x8*)(Bc + (wn + j * 16 + l16) * 64 + ko1);
    }
    if (t < 15) { STG(pBlo, Bn) pBlo += 64; }
    BAR();
    __builtin_amdgcn_s_setprio(1);
#pragma unroll
    for (int i = 0; i < 4; i++)
#pragma unroll
      for (int j = 0; j < 2; j++) {
        acc[i][j] = MFMA16(af[i][0], bfr[j][0], acc[i][j]);
        acc[i][j] = MFMA16(af[i][1], bfr[j][1], acc[i][j]);
      }
    __builtin_amdgcn_s_setprio(0);
    BAR();

#pragma unroll
    for (int j = 2; j < 4; j++) {
      bfr[j][0] = *(const bf16x8*)(Bc + (wn + j * 16 + l16) * 64 + ko0);
      bfr[j][1] = *(const bf16x8*)(Bc + (wn + j * 16 + l16) * 64 + ko1);
    }
    if (t < 15) { STG(pBhi, Bn + 8192) pBhi += 64; }
    BAR();
    __builtin_amdgcn_s_setprio(1);
#pragma unroll
    for (int i = 0; i < 4; i++)
#pragma unroll
      for (int j = 2; j < 4; j++) {
        acc[i][j] = MFMA16(af[i][0], bfr[j][0], acc[i][j]);
        acc[i][j] = MFMA16(af[i][1], bfr[j][1], acc[i][j]);
      }
    __builtin_amdgcn_s_setprio(0);
    BAR();

#pragma unroll
    for (int i = 0; i < 4; i++) {
      af[i][0] = *(const bf16x8*)(Ac + (wm + (i + 4) * 16 + l16) * 64 + ko0);
      af[i][1] = *(const bf16x8*)(Ac + (wm + (i + 4) * 16 + l16) * 64 + ko1);
    }
    if (t < 14) { STG(pAlo, An) pAlo += 64; }
    BAR();
    __builtin_amdgcn_s_setprio(1);
#pragma unroll
    for (int i = 0; i < 4; i++)
#pragma unroll
      for (int j = 0; j < 2; j++) {
        acc[i + 4][j] = MFMA16(af[i][0], bfr[j][0], acc[i + 4][j]);
        acc[i + 4][j] = MFMA16(af[i][1], bfr[j][1], acc[i + 4][j]);
      }
    __builtin_amdgcn_s_setprio(0);
    BAR();

    if (t < 14) {
      STG(pAhi, An + 8192) pAhi += 64;
      asm volatile("s_waitcnt vmcnt(4)" ::: "memory");
    } else if (t == 14) {
      asm volatile("s_waitcnt vmcnt(0)" ::: "memory");
    }
    BAR();
    __builtin_amdgcn_s_setprio(1);
#pragma unroll
    for (int i = 0; i < 4; i++)
#pragma unroll
      for (int j = 2; j < 4; j++) {
        acc[i + 4][j] = MFMA16(af[i][0], bfr[j][0], acc[i + 4][j]);
        acc[i + 4][j] = MFMA16(af[i][1], bfr[j][1], acc[i + 4][j]);
      }
    __builtin_amdgcn_s_setprio(0);
    BAR();
  }
#undef STG
#undef BAR

  const int tq = n0 >> 10;
#pragma unroll
  for (int i = 0; i < 8; i++) {
    const int rowb = m0 + wm + i * 16 + quad * 4;
    const int b = rowb >> 11, s0r = rowb & 2047;
#pragma unroll
    for (int j = 0; j < 4; j++) {
      const int col = n0 + wn + j * 16 + l16;
      const int h = (col >> 6) & 15, d = col & 63;
      if (tq == 2) {
        b16x4 v4;
#pragma unroll
        for (int r = 0; r < 4; r++) v4[r] = (bf16)acc[i][j][r];
        *(b16x4*)(VTo + ((size_t)(b * NH + h) * DH + d) * S_LEN + s0r) = v4;
      } else {
#pragma unroll
        for (int r = 0; r < 4; r++) {
          const float v = acc[i][j][r];
          if (tq == 0)
            Qo[((size_t)(b * NH + h) * S_LEN + s0r + r) * DH + d] = (bf16)(v * 0.125f);
          else
            Ko[((size_t)(b * NH + h) * S_LEN + s0r + r) * DH + d] = (bf16)v;
        }
      }
    }
  }
}

// ---------------------------------------------------------------------------
// GEMM 2: out = AO @ Woutb^T -> fp32. 64x64 tile, grid 1024 = 4 blocks/CU
// = 16 waves/CU (round-7 lever pushed further: 1->2 blocks/CU was -7.6us;
// 2->4 targets the remaining latency exposure). 4 waves, per-wave 32x32 =
// acc[2][2]; A+B tiles 8KB; A/B panels re-read from L2 (256MB agg @34.5TB/s
// — not binding).
// ---------------------------------------------------------------------------
#define BK  32
#define BM2 64
#define BN2 64

__global__ __launch_bounds__(256) void gemm_out_kernel(
    const bf16* __restrict__ A, const bf16* __restrict__ W,
    float* __restrict__ Out) {
  __shared__ __align__(16) bf16 As[BM2 * BK];   // 4 KB
  __shared__ __align__(16) bf16 Bs[BN2 * BK];   // 4 KB
  const int tid  = threadIdx.x;
  const int wave = tid >> 6, lane = tid & 63;
  const int quad = lane >> 4, l16 = lane & 15;
  const int m0 = blockIdx.y * BM2;
  const int n0 = blockIdx.x * BN2;
  const int wm = (wave >> 1) * 32, wn = (wave & 1) * 32;
  f32x4 acc[2][2] = {};
  const int c0 = tid;
  for (int k0 = 0; k0 < D_MODEL; k0 += BK) {
    // A tile: 64 rows x 32 cols = 256 chunks (1/thread); B same
    async_lds16(A + (size_t)(m0 + (c0 >> 2)) * D_MODEL + k0 + (c0 & 3) * 8,
                As + c0 * 8);
    async_lds16(W + (size_t)(n0 + (c0 >> 2)) * D_MODEL + k0 + (c0 & 3) * 8,
                Bs + c0 * 8);
    __syncthreads();
    bf16x8 af[2], bfr[2];
#pragma unroll
    for (int i = 0; i < 2; i++)
      af[i] = *(const bf16x8*)(As + (wm + i * 16 + l16) * BK + quad * 8);
#pragma unroll
    for (int j = 0; j < 2; j++)
      bfr[j] = *(const bf16x8*)(Bs + (wn + j * 16 + l16) * BK + quad * 8);
#pragma unroll
    for (int i = 0; i < 2; i++)
#pragma unroll
      for (int j = 0; j < 2; j++)
        acc[i][j] = MFMA16(af[i], bfr[j], acc[i][j]);
    __syncthreads();
  }
#pragma unroll
  for (int i = 0; i < 2; i++) {
    const int rowb = m0 + wm + i * 16 + quad * 4;
#pragma unroll
    for (int j = 0; j < 2; j++) {
      const int col = n0 + wn + j * 16 + l16;
#pragma unroll
      for (int r = 0; r < 4; r++)
        Out[(size_t)(rowb + r) * D_MODEL + col] = acc[i][j][r];
    }
  }
}

// ---------------------------------------------------------------------------
// Flash attention v10b (round-10 best, 46.5us, clean: VGPR 64, no scratch):
// 32 q/wave, grid 512 = 2 blocks/CU = 4 waves/SIMD; single barrier/iter;
// in-register softmax via cvt_pk+permlane; V read inline.
// mfma_f32_32x32x16_bf16 layouts (m74/m101): C col=lane&31,
// row=(r&3)+8*(r>>2)+4*(lane>>5); A row=lane&31,k=hi*8+j; B col=lane&31.
// ---------------------------------------------------------------------------
__global__ __launch_bounds__(512, 4) void attn_kernel(
    const bf16* __restrict__ Q, const bf16* __restrict__ K,
    const bf16* __restrict__ VT, bf16* __restrict__ AO) {
  __shared__ __align__(16) bf16 smem[2][2][2 * 64 * 64];  // [kv-grp][buf][K|V] 64KB

  const int tid  = threadIdx.x;
  const int lane = tid & 63;
  const int wave = tid >> 6;
  const int g    = wave >> 2;      // kv-split group (0/1)
  const int qw   = wave & 3;       // q-wave within group
  const int l31  = lane & 31;
  const int hi   = lane >> 5;
  const int sw   = l31 & 7;        // read-side XOR swizzle key

  // XCD-bijective remap: 64 consecutive logical blocks (4 heads) per XCD
  const int bid = (blockIdx.x & 7) * 64 + (blockIdx.x >> 3);
  const int qb  = bid & 15;        // 2048/128
  const int bh  = bid >> 4;        // 0..31

  const bf16* qp = Q  + ((size_t)bh * S_LEN + qb * 128 + qw * 32 + l31) * DH;
  const bf16* kp = K  + (size_t)bh * S_LEN * DH;
  const bf16* vp = VT + (size_t)bh * DH * S_LEN;

  // Q B-fragments: col=q=l31, k-rows = dk*16 + hi*8 + j
  bf16x8 qf[4];
#pragma unroll
  for (int dk = 0; dk < 4; dk++)
    qf[dk] = *(const bf16x8*)(qp + dk * 16 + hi * 8);

  // staging: 256 threads/group move K(8KB)+V(8KB) as 4x16B chunks/thread.
  // LDS dest linear; global src pre-swizzled (rule 21).
  const int gtid = tid & 255;
  const int cid0 = gtid, cid1 = gtid + 256;
  const int r0 = cid0 >> 3, c0 = (cid0 & 7) ^ (r0 & 7);
  const int r1 = cid1 >> 3, c1 = (cid1 & 7) ^ (r1 & 7);
  const bf16* ka0 = kp + (size_t)(g * 64 + r0) * DH + c0 * 8;
  const bf16* ka1 = kp + (size_t)(g * 64 + r1) * DH + c1 * 8;
  const bf16* va0 = vp + (size_t)r0 * S_LEN + g * 64 + c0 * 8;
  const bf16* va1 = vp + (size_t)r1 * S_LEN + g * 64 + c1 * 8;
  const int ld0 = cid0 * 8, ld1 = cid1 * 8;

  f32x16 oT[2] = {};
  float lsum = 0.f;

  bf16* sg = &smem[g][0][0];

#define STAGE(B)                                                                 \
  {                                                                              \
    bf16* s = sg + (B) * (2 * 64 * 64);                                          \
    async_lds16(ka0, s + ld0);                                                   \
    async_lds16(ka1, s + ld1);                                                   \
    async_lds16(va0, s + 4096 + ld0);                                            \
    async_lds16(va1, s + 4096 + ld1);                                            \
    ka0 += 8192; ka1 += 8192; va0 += 128; va1 += 128;                            \
  }

  STAGE(0)

#pragma unroll 2
  for (int t = 0; t < 16; t++) {
    const int cur = t & 1;
    asm volatile("s_waitcnt vmcnt(0)" ::: "memory");   // this wave's tile-t loads landed
    __builtin_amdgcn_s_barrier();                      // all landed; prev-buf reads done
    if (t < 15) {
      STAGE(cur ^ 1)
    }

    const bf16* sb = sg + cur * (2 * 64 * 64);

    // S^T[key][q]
    f32x16 st[2] = {};
    __builtin_amdgcn_s_setprio(1);
#pragma unroll
    for (int kt = 0; kt < 2; kt++)
#pragma unroll
      for (int dk = 0; dk < 4; dk++) {
        const bf16x8 kf = *(const bf16x8*)(sb + (kt * 32 + l31) * 64 +
                                           (((dk * 2 + hi) ^ sw) * 8));
        st[kt] = __builtin_amdgcn_mfma_f32_32x32x16_bf16(kf, qf[dk], st[kt], 0, 0, 0);
      }
    __builtin_amdgcn_s_setprio(0);

    // exp -> pack -> permlane swap -> PV (V read inline; no hoist)
#pragma unroll
    for (int kt = 0; kt < 2; kt++)
#pragma unroll
      for (int hk = 0; hk < 2; hk++) {
        const int ks = kt * 2 + hk;
        float e0[8];
#pragma unroll
        for (int r = 0; r < 8; r++) e0[r] = __expf(st[kt][hk * 8 + r]);
        lsum += ((e0[0] + e0[1]) + (e0[2] + e0[3])) + ((e0[4] + e0[5]) + (e0[6] + e0[7]));
        uint32 p00, p01, p02, p03;
        asm("v_cvt_pk_bf16_f32 %0, %1, %2" : "=v"(p00) : "v"(e0[0]), "v"(e0[1]));
        asm("v_cvt_pk_bf16_f32 %0, %1, %2" : "=v"(p01) : "v"(e0[2]), "v"(e0[3]));
        asm("v_cvt_pk_bf16_f32 %0, %1, %2" : "=v"(p02) : "v"(e0[4]), "v"(e0[5]));
        asm("v_cvt_pk_bf16_f32 %0, %1, %2" : "=v"(p03) : "v"(e0[6]), "v"(e0[7]));
        asm("v_permlane32_swap_b32 %0, %1" : "+v"(p00), "+v"(p02));
        asm("v_permlane32_swap_b32 %0, %1" : "+v"(p01), "+v"(p03));
        union { uint32 u[4]; bf16x8 v; } pf;
        pf.u[0] = p00; pf.u[1] = p01; pf.u[2] = p02; pf.u[3] = p03;
        __builtin_amdgcn_s_setprio(1);
#pragma unroll
        for (int dt = 0; dt < 2; dt++) {
          const bf16x8 vf = *(const bf16x8*)(sb + 4096 + (dt * 32 + l31) * 64 +
                                             (((ks * 2 + hi) ^ sw) * 8));
          oT[dt] = __builtin_amdgcn_mfma_f32_32x32x16_bf16(vf, pf.v, oT[dt], 0, 0, 0);
        }
        __builtin_amdgcn_s_setprio(0);
      }
  }
#undef STAGE

  __syncthreads();   // all reads of smem done before merge overlays it

  // column total: partner lane (lane^32) holds the other 32 key-rows
  lsum += __shfl_xor(lsum, 32);

  // kv-split merge (group 1 -> group 0): 256 lane-slots x 128 B = 32 KB
  float* mO = (float*)&smem[0][0][0];
  float* mL = mO + 256 * 32;                     // 1 KB
  const int mrow = qw * 64 + lane;

  if (g == 1) {
#pragma unroll
    for (int j = 0; j < 8; j++) {
      const int dt = j >> 2, rb = (j & 3) * 4;
      f32x4 c = { oT[dt][rb], oT[dt][rb + 1], oT[dt][rb + 2], oT[dt][rb + 3] };
      *(f32x4*)((char*)mO + mrow * 128 + ((j ^ (lane & 7)) * 16)) = c;
    }
    mL[mrow] = lsum;
  }
  __syncthreads();
  if (g == 0) {
#pragma unroll
    for (int j = 0; j < 8; j++) {
      const int dt = j >> 2, rb = (j & 3) * 4;
      const f32x4 c = *(const f32x4*)((char*)mO + mrow * 128 + ((j ^ (lane & 7)) * 16));
#pragma unroll
      for (int rr = 0; rr < 4; rr++) oT[dt][rb + rr] += c[rr];
    }
    lsum += mL[mrow];

    const float inv = 1.0f / (lsum + 1e-6f);
    const int b = bh >> 4, h = bh & 15;
    const int srow = qb * 128 + qw * 32 + l31;   // q = col = l31 per lane
    const size_t base = (size_t)(b * S_LEN + srow) * D_MODEL + h * DH;
#pragma unroll
    for (int dt = 0; dt < 2; dt++)
#pragma unroll
      for (int rg = 0; rg < 4; rg++) {
        b16x4 o4;
#pragma unroll
        for (int rr = 0; rr < 4; rr++) o4[rr] = (bf16)(oT[dt][rg * 4 + rr] * inv);
        *(b16x4*)(AO + base + dt * 32 + rg * 8 + hi * 4) = o4;
      }
  }
}

extern "C" void kernel_launch(void* const* d_in, const int* in_sizes, int n_in,
                              void* d_out, int out_size, void* d_ws, size_t ws_size,
                              hipStream_t stream) {
  const float* x    = (const float*)d_in[0];
  const float* wqkv = (const float*)d_in[1];
  const float* wout = (const float*)d_in[2];
  float* out = (float*)d_out;

  // ws (32 MB): [Q 8MB][K 8MB][VT 8MB][xb 8MB -> AO after gemm_qkv]
  bf16* Q  = (bf16*)d_ws;
  bf16* K  = Q  + (size_t)TOKENS * D_MODEL;
  bf16* VT = K  + (size_t)TOKENS * D_MODEL;
  bf16* xb = VT + (size_t)TOKENS * D_MODEL;
  bf16* AO = xb;                       // xb dead after gemm_qkv
  bf16* wqkvb = (bf16*)d_out;          // d_out dead until gemm_out
  bf16* woutb = Q;                     // Q dead after attn

  const int nx = TOKENS * D_MODEL / 8;          // 524288
  const int nw = 3 * D_MODEL * D_MODEL / 8;     // 393216
  const int no = D_MODEL * D_MODEL / 8;         // 131072
  convert2_kernel<<<dim3((nx + nw) / 256), dim3(256), 0, stream>>>(
      x, xb, nx, wqkv, wqkvb, nw);

  gemm_qkv_kernel<<<dim3(3 * D_MODEL / 256, TOKENS / 256), dim3(512),
                    131072, stream>>>(xb, wqkvb, Q, K, VT);

  attn_kernel<<<dim3(BATCH * NH * (S_LEN / 128)), dim3(512), 0, stream>>>(Q, K, VT, AO);

  convert2_kernel<<<dim3(no / 256), dim3(256), 0, stream>>>(
      wout, woutb, no, wout, woutb, 0);

  gemm_out_kernel<<<dim3(D_MODEL / BN2, TOKENS / BM2), dim3(256), 0, stream>>>(
      AO, woutb, out);
}

// Round 12
// 175.487 us; speedup vs baseline: 1.0356x; 1.0356x over previous
//
#include <hip/hip_runtime.h>
#include <hip/hip_bf16.h>
#include <stdint.h>

#define S_LEN   2048
#define D_MODEL 1024
#define NH      16
#define DH      64
#define BATCH   2
#define TOKENS  (BATCH * S_LEN)   // 4096

typedef __bf16 bf16;
typedef __bf16 bf16x8 __attribute__((ext_vector_type(8)));
typedef __bf16 b16x4  __attribute__((ext_vector_type(4)));
typedef float  f32x4  __attribute__((ext_vector_type(4)));
typedef float  f32x16 __attribute__((ext_vector_type(16)));
typedef unsigned int uint32;

__device__ __forceinline__ void async_lds16(const void* g, void* l) {
  __builtin_amdgcn_global_load_lds((__attribute__((address_space(1))) void*)g,
                                   (__attribute__((address_space(3))) void*)l,
                                   16, 0, 0);
}

#define MFMA16(a, b, c) __builtin_amdgcn_mfma_f32_16x16x32_bf16((a), (b), (c), 0, 0, 0)

// Q pre-scale: 1/sqrt(Dh) * log2(e), so attn softmax can use raw v_exp_f32
// (2^x) with no per-element mul: exp2(qk*0.125*log2e) == e^(qk*0.125).
#define QSCALE 0.18033688011112042f

// ---------------------------------------------------------------------------
// fused fp32 -> bf16 bulk convert over two ranges (8 elems/thread).
// ---------------------------------------------------------------------------
__global__ __launch_bounds__(256) void convert2_kernel(
    const float* __restrict__ s0, bf16* __restrict__ d0, int n0,
    const float* __restrict__ s1, bf16* __restrict__ d1, int n1) {
  int i = blockIdx.x * 256 + threadIdx.x;
  const float* s;
  bf16* d;
  if (i < n0) {
    s = s0 + (size_t)i * 8; d = d0 + (size_t)i * 8;
  } else {
    i -= n0;
    if (i >= n1) return;
    s = s1 + (size_t)i * 8; d = d1 + (size_t)i * 8;
  }
  const f32x4 a = *(const f32x4*)s;
  const f32x4 b = *(const f32x4*)(s + 4);
  bf16x8 o;
#pragma unroll
  for (int j = 0; j < 4; j++) { o[j] = (bf16)a[j]; o[j + 4] = (bf16)b[j]; }
  *(bf16x8*)d = o;
}

// ---------------------------------------------------------------------------
// GEMM 1: 8-phase 256x256 (m201 template) — round-8 verified.
// ---------------------------------------------------------------------------
__global__ __launch_bounds__(512, 2) void gemm_qkv_kernel(
    const bf16* __restrict__ X, const bf16* __restrict__ W,
    bf16* __restrict__ Qo, bf16* __restrict__ Ko, bf16* __restrict__ VTo) {
  extern __shared__ __align__(16) bf16 smem[];
  bf16* const Asb = smem;            // [2][16384] elems (64 KB)
  bf16* const Bsb = smem + 32768;    // [2][16384] elems (64 KB)

  const int tid  = threadIdx.x;
  const int wave = tid >> 6, lane = tid & 63;
  const int quad = lane >> 4, l16 = lane & 15;
  const int wm = (wave >> 2) * 128;
  const int wn = (wave & 3) * 64;
  const int m0 = blockIdx.y * 256;
  const int n0 = blockIdx.x * 256;

  const int rowc  = tid >> 3;
  const int koffc = ((tid & 7) ^ (rowc & 7)) * 8;
  const bf16* pAlo = X + (size_t)(m0 + rowc) * D_MODEL + koffc;
  const bf16* pAhi = X + (size_t)(m0 + 128 + rowc) * D_MODEL + koffc;
  const bf16* pBlo = W + (size_t)(n0 + rowc) * D_MODEL + koffc;
  const bf16* pBhi = W + (size_t)(n0 + 128 + rowc) * D_MODEL + koffc;
  const int ldc = tid * 8;

  const int swr = l16 & 7;
  const int ko0 = ((0 + quad) ^ swr) * 8;
  const int ko1 = ((4 + quad) ^ swr) * 8;

  f32x4 acc[8][4] = {};
  bf16x8 af[4][2], bfr[4][2];

#define STG(P, LB)                                                        \
  { async_lds16((P), (LB) + ldc);                                         \
    async_lds16((P) + (size_t)64 * D_MODEL, (LB) + ldc + 4096); }

#define BAR()                                                             \
  { asm volatile("" ::: "memory");                                        \
    __builtin_amdgcn_s_barrier();                                         \
    asm volatile("" ::: "memory"); }

  STG(pAlo, Asb)                 pAlo += 64;
  STG(pAhi, Asb + 8192)          pAhi += 64;
  STG(pBlo, Bsb)                 pBlo += 64;
  STG(pBhi, Bsb + 8192)          pBhi += 64;
  STG(pAlo, Asb + 16384)         pAlo += 64;
  STG(pAhi, Asb + 16384 + 8192)  pAhi += 64;
  asm volatile("s_waitcnt vmcnt(4)" ::: "memory");
  __builtin_amdgcn_s_barrier();

#pragma unroll 2
  for (int t = 0; t < 16; t++) {
    const int cur = t & 1;
    const bf16* Ac = Asb + cur * 16384;
    const bf16* Bc = Bsb + cur * 16384;
    bf16* An = Asb + cur * 16384;
    bf16* Bn = Bsb + (cur ^ 1) * 16384;

#pragma unroll
    for (int i = 0; i < 4; i++) {
      af[i][0] = *(const bf16x8*)(Ac + (wm + i * 16 + l16) * 64 + ko0);
      af[i][1] = *(const bf16x8*)(Ac + (wm + i * 16 + l16) * 64 + ko1);
    }
#pragma unroll
    for (int j = 0; j < 2; j++) {
      bfr[j][0] = *(const bf16x8*)(Bc + (wn + j * 16 + l16) * 64 + ko0);
      bfr[j][1] = *(const bf16x8*)(Bc + (wn + j * 16 + l16) * 64 + ko1);
    }
    if (t < 15) { STG(pBlo, Bn) pBlo += 64; }
    BAR();
    __builtin_amdgcn_s_setprio(1);
#pragma unroll
    for (int i = 0; i < 4; i++)
#pragma unroll
      for (int j = 0; j < 2; j++) {
        acc[i][j] = MFMA16(af[i][0], bfr[j][0], acc[i][j]);
        acc[i][j] = MFMA16(af[i][1], bfr[j][1], acc[i][j]);
      }
    __builtin_amdgcn_s_setprio(0);
    BAR();

#pragma unroll
    for (int j = 2; j < 4; j++) {
      bfr[j][0] = *(const bf16x8*)(Bc + (wn + j * 16 + l16) * 64 + ko0);
      bfr[j][1] = *(const bf16x8*)(Bc + (wn + j * 16 + l16) * 64 + ko1);
    }
    if (t < 15) { STG(pBhi, Bn + 8192) pBhi += 64; }
    BAR();
    __builtin_amdgcn_s_setprio(1);
#pragma unroll
    for (int i = 0; i < 4; i++)
#pragma unroll
      for (int j = 2; j < 4; j++) {
        acc[i][j] = MFMA16(af[i][0], bfr[j][0], acc[i][j]);
        acc[i][j] = MFMA16(af[i][1], bfr[j][1], acc[i][j]);
      }
    __builtin_amdgcn_s_setprio(0);
    BAR();

#pragma unroll
    for (int i = 0; i < 4; i++) {
      af[i][0] = *(const bf16x8*)(Ac + (wm + (i + 4) * 16 + l16) * 64 + ko0);
      af[i][1] = *(const bf16x8*)(Ac + (wm + (i + 4) * 16 + l16) * 64 + ko1);
    }
    if (t < 14) { STG(pAlo, An) pAlo += 64; }
    BAR();
    __builtin_amdgcn_s_setprio(1);
#pragma unroll
    for (int i = 0; i < 4; i++)
#pragma unroll
      for (int j = 0; j < 2; j++) {
        acc[i + 4][j] = MFMA16(af[i][0], bfr[j][0], acc[i + 4][j]);
        acc[i + 4][j] = MFMA16(af[i][1], bfr[j][1], acc[i + 4][j]);
      }
    __builtin_amdgcn_s_setprio(0);
    BAR();

    if (t < 14) {
      STG(pAhi, An + 8192) pAhi += 64;
      asm volatile("s_waitcnt vmcnt(4)" ::: "memory");
    } else if (t == 14) {
      asm volatile("s_waitcnt vmcnt(0)" ::: "memory");
    }
    BAR();
    __builtin_amdgcn_s_setprio(1);
#pragma unroll
    for (int i = 0; i < 4; i++)
#pragma unroll
      for (int j = 2; j < 4; j++) {
        acc[i + 4][j] = MFMA16(af[i][0], bfr[j][0], acc[i + 4][j]);
        acc[i + 4][j] = MFMA16(af[i][1], bfr[j][1], acc[i + 4][j]);
      }
    __builtin_amdgcn_s_setprio(0);
    BAR();
  }
#undef STG
#undef BAR

  const int tq = n0 >> 10;
#pragma unroll
  for (int i = 0; i < 8; i++) {
    const int rowb = m0 + wm + i * 16 + quad * 4;
    const int b = rowb >> 11, s0r = rowb & 2047;
#pragma unroll
    for (int j = 0; j < 4; j++) {
      const int col = n0 + wn + j * 16 + l16;
      const int h = (col >> 6) & 15, d = col & 63;
      if (tq == 2) {
        b16x4 v4;
#pragma unroll
        for (int r = 0; r < 4; r++) v4[r] = (bf16)acc[i][j][r];
        *(b16x4*)(VTo + ((size_t)(b * NH + h) * DH + d) * S_LEN + s0r) = v4;
      } else {
#pragma unroll
        for (int r = 0; r < 4; r++) {
          const float v = acc[i][j][r];
          if (tq == 0)
            Qo[((size_t)(b * NH + h) * S_LEN + s0r + r) * DH + d] = (bf16)(v * QSCALE);
          else
            Ko[((size_t)(b * NH + h) * S_LEN + s0r + r) * DH + d] = (bf16)v;
        }
      }
    }
  }
}

// ---------------------------------------------------------------------------
// GEMM 2: out = AO @ Woutb^T -> fp32. 64x128 tile, grid 512 = 2 blocks/CU
// (round-7 verified best; round-11's 64x64 4-blocks/CU regressed ~3us from
// halved arithmetic intensity — reverted).
// ---------------------------------------------------------------------------
#define BK  32
#define BM2 64
#define BN2 128

__global__ __launch_bounds__(256) void gemm_out_kernel(
    const bf16* __restrict__ A, const bf16* __restrict__ W,
    float* __restrict__ Out) {
  __shared__ __align__(16) bf16 As[BM2 * BK];   // 4 KB
  __shared__ __align__(16) bf16 Bs[BN2 * BK];   // 8 KB
  const int tid  = threadIdx.x;
  const int wave = tid >> 6, lane = tid & 63;
  const int quad = lane >> 4, l16 = lane & 15;
  const int m0 = blockIdx.y * BM2;
  const int n0 = blockIdx.x * BN2;
  const int wm = (wave >> 1) * 32, wn = (wave & 1) * 64;
  f32x4 acc[2][4] = {};
  const int c0 = tid, c1 = tid + 256;
  for (int k0 = 0; k0 < D_MODEL; k0 += BK) {
    async_lds16(A + (size_t)(m0 + (c0 >> 2)) * D_MODEL + k0 + (c0 & 3) * 8,
                As + c0 * 8);
    async_lds16(W + (size_t)(n0 + (c0 >> 2)) * D_MODEL + k0 + (c0 & 3) * 8,
                Bs + c0 * 8);
    async_lds16(W + (size_t)(n0 + (c1 >> 2)) * D_MODEL + k0 + (c1 & 3) * 8,
                Bs + c1 * 8);
    __syncthreads();
    bf16x8 af[2], bfr[4];
#pragma unroll
    for (int i = 0; i < 2; i++)
      af[i] = *(const bf16x8*)(As + (wm + i * 16 + l16) * BK + quad * 8);
#pragma unroll
    for (int j = 0; j < 4; j++)
      bfr[j] = *(const bf16x8*)(Bs + (wn + j * 16 + l16) * BK + quad * 8);
#pragma unroll
    for (int i = 0; i < 2; i++)
#pragma unroll
      for (int j = 0; j < 4; j++)
        acc[i][j] = MFMA16(af[i], bfr[j], acc[i][j]);
    __syncthreads();
  }
#pragma unroll
  for (int i = 0; i < 2; i++) {
    const int rowb = m0 + wm + i * 16 + quad * 4;
#pragma unroll
    for (int j = 0; j < 4; j++) {
      const int col = n0 + wn + j * 16 + l16;
#pragma unroll
      for (int r = 0; r < 4; r++)
        Out[(size_t)(rowb + r) * D_MODEL + col] = acc[i][j][r];
    }
  }
}

// ---------------------------------------------------------------------------
// Flash attention v10c: v10b (round-10, 46.5us, VGPR 64, no scratch) with
// exp folded to raw v_exp_f32 (Q pre-scaled by log2e in gemm_qkv): saves
// 32 VALU muls + one dep-chain stage per iter per wave.
// 32 q/wave, grid 512 = 2 blocks/CU = 4 waves/SIMD; single barrier/iter;
// in-register softmax via cvt_pk+permlane; V read inline.
// mfma_f32_32x32x16_bf16 layouts (m74/m101): C col=lane&31,
// row=(r&3)+8*(r>>2)+4*(lane>>5); A row=lane&31,k=hi*8+j; B col=lane&31.
// ---------------------------------------------------------------------------
__global__ __launch_bounds__(512, 4) void attn_kernel(
    const bf16* __restrict__ Q, const bf16* __restrict__ K,
    const bf16* __restrict__ VT, bf16* __restrict__ AO) {
  __shared__ __align__(16) bf16 smem[2][2][2 * 64 * 64];  // [kv-grp][buf][K|V] 64KB

  const int tid  = threadIdx.x;
  const int lane = tid & 63;
  const int wave = tid >> 6;
  const int g    = wave >> 2;      // kv-split group (0/1)
  const int qw   = wave & 3;       // q-wave within group
  const int l31  = lane & 31;
  const int hi   = lane >> 5;
  const int sw   = l31 & 7;        // read-side XOR swizzle key

  // XCD-bijective remap: 64 consecutive logical blocks (4 heads) per XCD
  const int bid = (blockIdx.x & 7) * 64 + (blockIdx.x >> 3);
  const int qb  = bid & 15;        // 2048/128
  const int bh  = bid >> 4;        // 0..31

  const bf16* qp = Q  + ((size_t)bh * S_LEN + qb * 128 + qw * 32 + l31) * DH;
  const bf16* kp = K  + (size_t)bh * S_LEN * DH;
  const bf16* vp = VT + (size_t)bh * DH * S_LEN;

  // Q B-fragments: col=q=l31, k-rows = dk*16 + hi*8 + j
  bf16x8 qf[4];
#pragma unroll
  for (int dk = 0; dk < 4; dk++)
    qf[dk] = *(const bf16x8*)(qp + dk * 16 + hi * 8);

  // staging: 256 threads/group move K(8KB)+V(8KB) as 4x16B chunks/thread.
  // LDS dest linear; global src pre-swizzled (rule 21).
  const int gtid = tid & 255;
  const int cid0 = gtid, cid1 = gtid + 256;
  const int r0 = cid0 >> 3, c0 = (cid0 & 7) ^ (r0 & 7);
  const int r1 = cid1 >> 3, c1 = (cid1 & 7) ^ (r1 & 7);
  const bf16* ka0 = kp + (size_t)(g * 64 + r0) * DH + c0 * 8;
  const bf16* ka1 = kp + (size_t)(g * 64 + r1) * DH + c1 * 8;
  const bf16* va0 = vp + (size_t)r0 * S_LEN + g * 64 + c0 * 8;
  const bf16* va1 = vp + (size_t)r1 * S_LEN + g * 64 + c1 * 8;
  const int ld0 = cid0 * 8, ld1 = cid1 * 8;

  f32x16 oT[2] = {};
  float lsum = 0.f;

  bf16* sg = &smem[g][0][0];

#define STAGE(B)                                                                 \
  {                                                                              \
    bf16* s = sg + (B) * (2 * 64 * 64);                                          \
    async_lds16(ka0, s + ld0);                                                   \
    async_lds16(ka1, s + ld1);                                                   \
    async_lds16(va0, s + 4096 + ld0);                                            \
    async_lds16(va1, s + 4096 + ld1);                                            \
    ka0 += 8192; ka1 += 8192; va0 += 128; va1 += 128;                            \
  }

  STAGE(0)

#pragma unroll 2
  for (int t = 0; t < 16; t++) {
    const int cur = t & 1;
    asm volatile("s_waitcnt vmcnt(0)" ::: "memory");   // this wave's tile-t loads landed
    __builtin_amdgcn_s_barrier();                      // all landed; prev-buf reads done
    if (t < 15) {
      STAGE(cur ^ 1)
    }

    const bf16* sb = sg + cur * (2 * 64 * 64);

    // S^T[key][q]  (pre-scaled by log2e via QSCALE)
    f32x16 st[2] = {};
    __builtin_amdgcn_s_setprio(1);
#pragma unroll
    for (int kt = 0; kt < 2; kt++)
#pragma unroll
      for (int dk = 0; dk < 4; dk++) {
        const bf16x8 kf = *(const bf16x8*)(sb + (kt * 32 + l31) * 64 +
                                           (((dk * 2 + hi) ^ sw) * 8));
        st[kt] = __builtin_amdgcn_mfma_f32_32x32x16_bf16(kf, qf[dk], st[kt], 0, 0, 0);
      }
    __builtin_amdgcn_s_setprio(0);

    // raw v_exp_f32 (2^x) -> pack -> permlane swap -> PV (V read inline)
#pragma unroll
    for (int kt = 0; kt < 2; kt++)
#pragma unroll
      for (int hk = 0; hk < 2; hk++) {
        const int ks = kt * 2 + hk;
        float e0[8];
#pragma unroll
        for (int r = 0; r < 8; r++) {
          const float x = st[kt][hk * 8 + r];
          asm("v_exp_f32 %0, %1" : "=v"(e0[r]) : "v"(x));
        }
        lsum += ((e0[0] + e0[1]) + (e0[2] + e0[3])) + ((e0[4] + e0[5]) + (e0[6] + e0[7]));
        uint32 p00, p01, p02, p03;
        asm("v_cvt_pk_bf16_f32 %0, %1, %2" : "=v"(p00) : "v"(e0[0]), "v"(e0[1]));
        asm("v_cvt_pk_bf16_f32 %0, %1, %2" : "=v"(p01) : "v"(e0[2]), "v"(e0[3]));
        asm("v_cvt_pk_bf16_f32 %0, %1, %2" : "=v"(p02) : "v"(e0[4]), "v"(e0[5]));
        asm("v_cvt_pk_bf16_f32 %0, %1, %2" : "=v"(p03) : "v"(e0[6]), "v"(e0[7]));
        asm("v_permlane32_swap_b32 %0, %1" : "+v"(p00), "+v"(p02));
        asm("v_permlane32_swap_b32 %0, %1" : "+v"(p01), "+v"(p03));
        union { uint32 u[4]; bf16x8 v; } pf;
        pf.u[0] = p00; pf.u[1] = p01; pf.u[2] = p02; pf.u[3] = p03;
        __builtin_amdgcn_s_setprio(1);
#pragma unroll
        for (int dt = 0; dt < 2; dt++) {
          const bf16x8 vf = *(const bf16x8*)(sb + 4096 + (dt * 32 + l31) * 64 +
                                             (((ks * 2 + hi) ^ sw) * 8));
          oT[dt] = __builtin_amdgcn_mfma_f32_32x32x16_bf16(vf, pf.v, oT[dt], 0, 0, 0);
        }
        __builtin_amdgcn_s_setprio(0);
      }
  }
#undef STAGE

  __syncthreads();   // all reads of smem done before merge overlays it

  // column total: partner lane (lane^32) holds the other 32 key-rows
  lsum += __shfl_xor(lsum, 32);

  // kv-split merge (group 1 -> group 0): 256 lane-slots x 128 B = 32 KB
  float* mO = (float*)&smem[0][0][0];
  float* mL = mO + 256 * 32;                     // 1 KB
  const int mrow = qw * 64 + lane;

  if (g == 1) {
#pragma unroll
    for (int j = 0; j < 8; j++) {
      const int dt = j >> 2, rb = (j & 3) * 4;
      f32x4 c = { oT[dt][rb], oT[dt][rb + 1], oT[dt][rb + 2], oT[dt][rb + 3] };
      *(f32x4*)((char*)mO + mrow * 128 + ((j ^ (lane & 7)) * 16)) = c;
    }
    mL[mrow] = lsum;
  }
  __syncthreads();
  if (g == 0) {
#pragma unroll
    for (int j = 0; j < 8; j++) {
      const int dt = j >> 2, rb = (j & 3) * 4;
      const f32x4 c = *(const f32x4*)((char*)mO + mrow * 128 + ((j ^ (lane & 7)) * 16));
#pragma unroll
      for (int rr = 0; rr < 4; rr++) oT[dt][rb + rr] += c[rr];
    }
    lsum += mL[mrow];

    const float inv = 1.0f / (lsum + 1e-6f);
    const int b = bh >> 4, h = bh & 15;
    const int srow = qb * 128 + qw * 32 + l31;   // q = col = l31 per lane
    const size_t base = (size_t)(b * S_LEN + srow) * D_MODEL + h * DH;
#pragma unroll
    for (int dt = 0; dt < 2; dt++)
#pragma unroll
      for (int rg = 0; rg < 4; rg++) {
        b16x4 o4;
#pragma unroll
        for (int rr = 0; rr < 4; rr++) o4[rr] = (bf16)(oT[dt][rg * 4 + rr] * inv);
        *(b16x4*)(AO + base + dt * 32 + rg * 8 + hi * 4) = o4;
      }
  }
}

extern "C" void kernel_launch(void* const* d_in, const int* in_sizes, int n_in,
                              void* d_out, int out_size, void* d_ws, size_t ws_size,
                              hipStream_t stream) {
  const float* x    = (const float*)d_in[0];
  const float* wqkv = (const float*)d_in[1];
  const float* wout = (const float*)d_in[2];
  float* out = (float*)d_out;

  // ws (32 MB): [Q 8MB][K 8MB][VT 8MB][xb 8MB -> AO after gemm_qkv]
  bf16* Q  = (bf16*)d_ws;
  bf16* K  = Q  + (size_t)TOKENS * D_MODEL;
  bf16* VT = K  + (size_t)TOKENS * D_MODEL;
  bf16* xb = VT + (size_t)TOKENS * D_MODEL;
  bf16* AO = xb;                       // xb dead after gemm_qkv
  bf16* wqkvb = (bf16*)d_out;          // d_out dead until gemm_out
  bf16* woutb = Q;                     // Q dead after attn

  const int nx = TOKENS * D_MODEL / 8;          // 524288
  const int nw = 3 * D_MODEL * D_MODEL / 8;     // 393216
  const int no = D_MODEL * D_MODEL / 8;         // 131072
  convert2_kernel<<<dim3((nx + nw) / 256), dim3(256), 0, stream>>>(
      x, xb, nx, wqkv, wqkvb, nw);

  gemm_qkv_kernel<<<dim3(3 * D_MODEL / 256, TOKENS / 256), dim3(512),
                    131072, stream>>>(xb, wqkvb, Q, K, VT);

  attn_kernel<<<dim3(BATCH * NH * (S_LEN / 128)), dim3(512), 0, stream>>>(Q, K, VT, AO);

  convert2_kernel<<<dim3(no / 256), dim3(256), 0, stream>>>(
      wout, woutb, no, wout, woutb, 0);

  gemm_out_kernel<<<dim3(D_MODEL / BN2, TOKENS / BM2), dim3(256), 0, stream>>>(
      AO, woutb, out);
}